// Round 1
// 494.761 us; speedup vs baseline: 1.0251x; 1.0251x over previous
//
#include <hip/hip_runtime.h>
#include <math.h>

#define NPG 1000
#define KTOP 500
#define C 64
#define EPG 16000   // edges per graph = NPG * DEG

__device__ __forceinline__ float readlane_f(float v, int l) {
    return __uint_as_float(__builtin_amdgcn_readlane(__float_as_uint(v), (unsigned)l));
}
__device__ __forceinline__ int readlane_i(int v, int l) {
    return (int)__builtin_amdgcn_readlane((unsigned)v, (unsigned)l);
}

// ---------------- fused per-graph CSR build: count + scan + scatter in LDS ----------------
// One block per graph. Edge list is graph-major: edges [g*EPG,(g+1)*EPG) belong to
// graph g and node ids lie in [g*NPG,(g+1)*NPG). All scatter traffic stays in LDS;
// global csr (+ per-edge weight wcsr = dinv[src]) is written fully coalesced.
__global__ __launch_bounds__(256) void build_graph_k(const int* __restrict__ ei, int E,
                                                     int* __restrict__ deg,
                                                     float* __restrict__ dinv,
                                                     int* __restrict__ off,
                                                     int* __restrict__ csr,
                                                     float* __restrict__ wcsr) {
    int g = blockIdx.x, t = threadIdx.x;
    __shared__ int cnt[NPG];               // counts, then cursors
    __shared__ int soff[NPG];              // local start offsets
    __shared__ float sdinv[NPG];           // per-node 1/sqrt(deg+1), local
    __shared__ unsigned short lcsr[EPG];   // src local ids, dst-grouped
    __shared__ int red[256];
    const int gbase = g * NPG;
    const int ebase = g * EPG;
    const int* __restrict__ srcp = ei + ebase;
    const int* __restrict__ dstp = ei + E + ebase;

    for (int i = t; i < NPG; i += 256) cnt[i] = 0;
    __syncthreads();
    // phase 1: count in-degree (LDS atomics)
    for (int i = t; i < EPG; i += 256) atomicAdd(&cnt[dstp[i] - gbase], 1);
    __syncthreads();
    // phase 2: exclusive scan over 1000 counts (4 per thread + Hillis-Steele on 256)
    int base = t * 4;
    int v0 = 0, v1 = 0, v2 = 0, v3 = 0;
    if (base + 0 < NPG) v0 = cnt[base + 0];
    if (base + 1 < NPG) v1 = cnt[base + 1];
    if (base + 2 < NPG) v2 = cnt[base + 2];
    if (base + 3 < NPG) v3 = cnt[base + 3];
    int s = v0 + v1 + v2 + v3;
    red[t] = s;
    __syncthreads();
    for (int o = 1; o < 256; o <<= 1) {
        int xx = (t >= o) ? red[t - o] : 0;
        __syncthreads();
        red[t] += xx;
        __syncthreads();
    }
    int p = red[t] - s;                    // exclusive prefix
    if (base + 0 < NPG) { soff[base + 0] = p; p += v0; }
    if (base + 1 < NPG) { soff[base + 1] = p; p += v1; }
    if (base + 2 < NPG) { soff[base + 2] = p; p += v2; }
    if (base + 3 < NPG) { soff[base + 3] = p; p += v3; }
    __syncthreads();
    // outputs: deg, dinv, off (coalesced); stash dinv in LDS for wcsr emit
    for (int i = t; i < NPG; i += 256) {
        int d = cnt[i];
        deg[gbase + i] = d;
        float dv = 1.0f / sqrtf((float)(d + 1));
        dinv[gbase + i] = dv;
        sdinv[i] = dv;
        off[gbase + i] = ebase + soff[i];
    }
    __syncthreads();
    // reset cursors
    for (int i = t; i < NPG; i += 256) cnt[i] = soff[i];
    __syncthreads();
    // phase 3: scatter src into dst-grouped order (LDS cursor atomics + LDS writes)
    for (int i = t; i < EPG; i += 256) {
        int d = dstp[i] - gbase;
        int pos = atomicAdd(&cnt[d], 1);
        lcsr[pos] = (unsigned short)(srcp[i] - gbase);
    }
    __syncthreads();
    // phase 4: dump csr + wcsr as coalesced 16B stores (EPG % 4 == 0)
    int4* co = (int4*)(csr + ebase);
    float4* wo = (float4*)(wcsr + ebase);
    for (int i = t; i < EPG / 4; i += 256) {
        int l0 = lcsr[i * 4 + 0], l1 = lcsr[i * 4 + 1];
        int l2 = lcsr[i * 4 + 2], l3 = lcsr[i * 4 + 3];
        int4 v;
        v.x = gbase + l0; v.y = gbase + l1; v.z = gbase + l2; v.w = gbase + l3;
        co[i] = v;
        float4 w;
        w.x = sdinv[l0]; w.y = sdinv[l1]; w.z = sdinv[l2]; w.w = sdinv[l3];
        wo[i] = w;
    }
}

// ---------------- h = x @ W : register-tiled, 2 rows/thread, W in LDS ----------------
__global__ __launch_bounds__(256) void gemm_k(const float* __restrict__ x,
                                              const float* __restrict__ W,
                                              float* __restrict__ h, int N) {
    __shared__ float sW[C * C];
    int t = threadIdx.x;
    for (int i = t; i < C * C / 4; i += 256) ((float4*)sW)[i] = ((const float4*)W)[i];
    __syncthreads();
    int r0 = blockIdx.x * 512 + t;
    int r1 = r0 + 256;
    if (r0 >= N) return;
    bool has1 = (r1 < N);
    const float4* x0 = (const float4*)(x + (size_t)r0 * C);
    const float4* x1 = (const float4*)(x + (size_t)(has1 ? r1 : r0) * C);
    float acc0[C], acc1[C];
#pragma unroll
    for (int i = 0; i < C; ++i) { acc0[i] = 0.f; acc1[i] = 0.f; }
    float4 a0 = x0[0], a1 = x1[0];
    for (int k4 = 0; k4 < 16; ++k4) {
        float4 b0, b1;
        if (k4 < 15) { b0 = x0[k4 + 1]; b1 = x1[k4 + 1]; }
        const float4* wr = (const float4*)(sW + k4 * 4 * C);
        const float* a0f = (const float*)&a0;
        const float* a1f = (const float*)&a1;
#pragma unroll
        for (int c4 = 0; c4 < 16; ++c4) {
            float4 w[4];
            w[0] = wr[c4]; w[1] = wr[16 + c4]; w[2] = wr[32 + c4]; w[3] = wr[48 + c4];
            const float* wf = (const float*)w;
#pragma unroll
            for (int j = 0; j < 4; ++j) {
                float s0 = acc0[c4 * 4 + j], s1 = acc1[c4 * 4 + j];
#pragma unroll
                for (int kk = 0; kk < 4; ++kk) {
                    float wv = wf[kk * 4 + j];
                    s0 = fmaf(a0f[kk], wv, s0);
                    s1 = fmaf(a1f[kk], wv, s1);
                }
                acc0[c4 * 4 + j] = s0; acc1[c4 * 4 + j] = s1;
            }
        }
        a0 = b0; a1 = b1;
    }
    float4* h0 = (float4*)(h + (size_t)r0 * C);
#pragma unroll
    for (int q = 0; q < 16; ++q) h0[q] = ((float4*)acc0)[q];
    if (has1) {
        float4* h1 = (float4*)(h + (size_t)r1 * C);
#pragma unroll
        for (int q = 0; q < 16; ++q) h1[q] = ((float4*)acc1)[q];
    }
}

// ---------------- gather aggregation: one wave per node, lane = channel ----------------
// XCD-swizzled so each graph's h slice stays in one XCD's L2.
// Broadcast of (src, weight) via v_readlane (VALU/SALU) instead of ds_bpermute:
// the index j is wave-uniform, so readlane puts src in an SGPR and the gather
// address becomes saddr + lane*4 — no LDS-pipe traffic at all.
__global__ __launch_bounds__(256) void gather_k(const int* __restrict__ csr,
                                                const float* __restrict__ wcsr,
                                                const int* __restrict__ off,
                                                const int* __restrict__ deg,
                                                const float* __restrict__ h,
                                                const float* __restrict__ dinv,
                                                const float* __restrict__ bias,
                                                float* __restrict__ out2, int N, int B) {
    int b = blockIdx.x;
    int wave = threadIdx.x >> 6;
    int lane = threadIdx.x & 63;
    int node;
    if ((B & 7) == 0) {
        int xcd = b & 7, slot = b >> 3;
        int gpx = B >> 3;
        int g = xcd * gpx + slot / (NPG / 4);
        int blkin = slot % (NPG / 4);
        node = g * NPG + blkin * 4 + wave;
    } else {
        node = b * 4 + wave;
    }
    if (node >= N) return;
    int o0 = off[node], dg = deg[node];
    float di = dinv[node];
    float hv = h[(size_t)node * C + lane];
    int sv = 0; float wv = 0.f;
    if (lane < dg) { sv = csr[o0 + lane]; wv = wcsr[o0 + lane]; }
    float acc = 0.f;
    int jmax = dg < 64 ? dg : 64;
    int j = 0;
    for (; j + 4 <= jmax; j += 4) {
        int   s0 = readlane_i(sv, j + 0); float w0 = readlane_f(wv, j + 0);
        int   s1 = readlane_i(sv, j + 1); float w1 = readlane_f(wv, j + 1);
        int   s2 = readlane_i(sv, j + 2); float w2 = readlane_f(wv, j + 2);
        int   s3 = readlane_i(sv, j + 3); float w3 = readlane_f(wv, j + 3);
        float h0 = h[(size_t)s0 * C + lane];
        float h1 = h[(size_t)s1 * C + lane];
        float h2 = h[(size_t)s2 * C + lane];
        float h3 = h[(size_t)s3 * C + lane];
        acc = fmaf(h0, w0, acc);
        acc = fmaf(h1, w1, acc);
        acc = fmaf(h2, w2, acc);
        acc = fmaf(h3, w3, acc);
    }
    for (; j < jmax; ++j) {
        int s = readlane_i(sv, j); float w = readlane_f(wv, j);
        acc = fmaf(h[(size_t)s * C + lane], w, acc);
    }
    for (; j < dg; ++j) {          // deg > 64 fallback (astronomically rare)
        int s = csr[o0 + j];
        acc = fmaf(h[(size_t)s * C + lane], dinv[s], acc);
    }
    out2[(size_t)node * C + lane] = bias[lane] + di * acc + di * di * hv;
}

// ---------------- per-graph centroid: partial sums (4 blocks/graph) + finalize ----------------
__global__ void centroid_part_k(const float* __restrict__ out2, float* __restrict__ pcen) {
    int blk = blockIdx.x;
    int g = blk >> 2, p = blk & 3;
    int t = threadIdx.x;
    int c = t & 63, q = t >> 6;
    const float* base = out2 + (size_t)g * NPG * C;
    int n0 = p * 250, n1 = n0 + 250;
    float acc = 0.f;
    for (int n = n0 + q; n < n1; n += 4) acc += base[(size_t)n * C + c];
    __shared__ float red[256];
    red[t] = acc;
    __syncthreads();
    if (t < 64) pcen[(size_t)blk * C + t] = red[t] + red[64 + t] + red[128 + t] + red[192 + t];
}

__global__ void cen_fin_k(const float* __restrict__ pcen, float* __restrict__ cen,
                          float* __restrict__ cnorm) {
    int g = blockIdx.x, c = threadIdx.x;   // 64 threads
    float s = pcen[(size_t)(g * 4 + 0) * C + c] + pcen[(size_t)(g * 4 + 1) * C + c]
            + pcen[(size_t)(g * 4 + 2) * C + c] + pcen[(size_t)(g * 4 + 3) * C + c];
    float m = s / 1000.0f;
    cen[g * C + c] = m;
    float v = m * m;
    for (int o = 32; o > 0; o >>= 1) v += __shfl_down(v, o, 64);
    if (c == 0) cnorm[g] = sqrtf(v);
}

// cosine similarity of each node row vs its graph centroid
__global__ void score_k(const float* __restrict__ out2, const float* __restrict__ cen,
                        const float* __restrict__ cnorm, float* __restrict__ score, int N) {
    int i = blockIdx.x * 256 + threadIdx.x;
    if (i < N) {
        int g = i / NPG;
        const float4* xr = (const float4*)(out2 + (size_t)i * C);
        const float4* cr = (const float4*)(cen + g * C);
        float num = 0.f, sq = 0.f;
#pragma unroll
        for (int q = 0; q < 16; ++q) {
            float4 a = xr[q], b = cr[q];
            num += a.x * b.x + a.y * b.y + a.z * b.z + a.w * b.w;
            sq  += a.x * a.x + a.y * a.y + a.z * a.z + a.w * a.w;
        }
        float den = sqrtf(sq) * cnorm[g] + 1e-8f;
        score[i] = num / den;
    }
}

// per-graph KL(softmax || uniform) — score row staged in LDS (one global pass)
__global__ void softmax_kl_k(const float* __restrict__ score, float* __restrict__ o_kl) {
    int g = blockIdx.x, t = threadIdx.x;
    __shared__ float ss[NPG];
    __shared__ float red[256];
    const float4* s4 = (const float4*)(score + (size_t)g * NPG);
    for (int i = t; i < NPG / 4; i += 256) ((float4*)ss)[i] = s4[i];
    __syncthreads();
    float mx = -INFINITY;
    for (int i = t; i < NPG; i += 256) mx = fmaxf(mx, ss[i]);
    red[t] = mx;
    __syncthreads();
    for (int w = 128; w > 0; w >>= 1) { if (t < w) red[t] = fmaxf(red[t], red[t + w]); __syncthreads(); }
    mx = red[0];
    __syncthreads();
    float se = 0.f;
    for (int i = t; i < NPG; i += 256) se += expf(ss[i] - mx);
    red[t] = se;
    __syncthreads();
    for (int w = 128; w > 0; w >>= 1) { if (t < w) red[t] += red[t + w]; __syncthreads(); }
    float lse = logf(red[0]);
    __syncthreads();
    float kl = 0.f;
    const float ln_npg = 6.9077552790f;
    for (int i = t; i < NPG; i += 256) {
        float lp = ss[i] - mx - lse;
        kl += expf(lp) * (lp + ln_npg);
    }
    red[t] = kl;
    __syncthreads();
    for (int w = 128; w > 0; w >>= 1) { if (t < w) red[t] += red[t + w]; __syncthreads(); }
    if (t == 0) o_kl[g] = red[0];
}

// ---------------- per-graph full descending stable argsort (bitonic, 1024) ----------------
__global__ void sort_k(const float* __restrict__ score, int* __restrict__ sidx,
                       float* __restrict__ o_ind) {
    __shared__ unsigned long long kk[1024];
    int g = blockIdx.x, t = threadIdx.x;          // 512 threads
    for (int i = t; i < 1024; i += 512) {
        unsigned long long v;
        if (i < NPG) {
            unsigned u = __float_as_uint(score[(size_t)g * NPG + i]);
            u = (u & 0x80000000u) ? ~u : (u | 0x80000000u);
            v = ((unsigned long long)(~u) << 32) | (unsigned)i;
        } else {
            v = ~0ULL;
        }
        kk[i] = v;
    }
    __syncthreads();
    for (int k = 2; k <= 1024; k <<= 1) {
        for (int j = k >> 1; j > 0; j >>= 1) {
            for (int i = t; i < 1024; i += 512) {
                int ixj = i ^ j;
                if (ixj > i) {
                    unsigned long long a = kk[i], b = kk[ixj];
                    bool up = ((i & k) == 0);
                    if ((a > b) == up) { kk[i] = b; kk[ixj] = a; }
                }
            }
            __syncthreads();
        }
    }
    for (int i = t; i < NPG; i += 512) {
        int idx = (int)(kk[i] & 0xFFFFFFFFULL);
        sidx[(size_t)g * NPG + i] = idx;
        o_ind[(size_t)g * NPG + i] = (float)idx;
    }
}

// ---------------- top-K gather: x_new, perm, batch_new, mapping ----------------
__global__ void topk_k(const int* __restrict__ sidx, const float* __restrict__ score,
                       const float* __restrict__ out2, int* __restrict__ mapping,
                       float* __restrict__ o_xnew, float* __restrict__ o_batch,
                       float* __restrict__ o_perm, int BK) {
    int j = blockIdx.x * 256 + threadIdx.x;
    if (j < BK) {
        int b = j / KTOP, r = j - b * KTOP;
        int node = sidx[(size_t)b * NPG + r];
        int gn = b * NPG + node;
        mapping[gn] = j;
        o_perm[j] = (float)gn;
        o_batch[j] = (float)b;
        float tn = tanhf(score[gn]);
        const float4* src = (const float4*)(out2 + (size_t)gn * C);
        float4* dst = (float4*)(o_xnew + (size_t)j * C);
#pragma unroll
        for (int q = 0; q < 16; ++q) {
            float4 v = src[q];
            v.x *= tn; v.y *= tn; v.z *= tn; v.w *= tn;
            dst[q] = v;
        }
    }
}

// ---------------- edge re-index + mask + attr (x4 vectorized; E % 4 == 0) ----------------
__global__ void edge_out_k(const int* __restrict__ ei, const float* __restrict__ eattr,
                           const int* __restrict__ mapping, float* __restrict__ o_newei,
                           float* __restrict__ o_eattr, float* __restrict__ o_mask, int E) {
    int e4 = blockIdx.x * 256 + threadIdx.x;
    int q = E >> 2;
    if (e4 < q) {
        int4 sidx = ((const int4*)ei)[e4];
        int4 didx = ((const int4*)ei)[q + e4];
        int a0 = mapping[sidx.x], a1 = mapping[sidx.y], a2 = mapping[sidx.z], a3 = mapping[sidx.w];
        int b0 = mapping[didx.x], b1 = mapping[didx.y], b2 = mapping[didx.z], b3 = mapping[didx.w];
        float4 f0 = { (float)a0, (float)a1, (float)a2, (float)a3 };
        float4 f1 = { (float)b0, (float)b1, (float)b2, (float)b3 };
        ((float4*)o_newei)[e4] = f0;
        ((float4*)o_newei)[q + e4] = f1;
        float4 at = ((const float4*)eattr)[e4];
        float4 mk, ea;
        mk.x = (a0 >= 0 && b0 >= 0) ? 1.0f : 0.0f;
        mk.y = (a1 >= 0 && b1 >= 0) ? 1.0f : 0.0f;
        mk.z = (a2 >= 0 && b2 >= 0) ? 1.0f : 0.0f;
        mk.w = (a3 >= 0 && b3 >= 0) ? 1.0f : 0.0f;
        ea.x = mk.x != 0.0f ? at.x : 0.0f;
        ea.y = mk.y != 0.0f ? at.y : 0.0f;
        ea.z = mk.z != 0.0f ? at.z : 0.0f;
        ea.w = mk.w != 0.0f ? at.w : 0.0f;
        ((float4*)o_mask)[e4] = mk;
        ((float4*)o_eattr)[e4] = ea;
    }
}

extern "C" void kernel_launch(void* const* d_in, const int* in_sizes, int n_in,
                              void* d_out, int out_size, void* d_ws, size_t ws_size,
                              hipStream_t stream) {
    (void)n_in; (void)out_size; (void)ws_size;
    const float* x     = (const float*)d_in[1];
    const int*   ei    = (const int*)d_in[2];
    const float* eattr = (const float*)d_in[3];
    const float* W     = (const float*)d_in[5];
    const float* bias  = (const float*)d_in[6];

    const int N  = in_sizes[1] / C;    // 256000
    const int E  = in_sizes[2] / 2;    // 4096000
    const int B  = N / NPG;            // 256
    const int BK = B * KTOP;           // 128000

    // workspace layout
    char* wsp = (char*)d_ws;
    float* out2    = (float*)wsp; wsp += (size_t)N * C * 4;   // 65.5 MB
    float* dinv    = (float*)wsp; wsp += (size_t)N * 4;
    float* score   = (float*)wsp; wsp += (size_t)N * 4;
    float* cen     = (float*)wsp; wsp += (size_t)B * C * 4;
    float* cnorm   = (float*)wsp; wsp += 1024;
    int*   sidx    = (int*)wsp;   wsp += (size_t)B * NPG * 4;
    int*   mapping = (int*)wsp;   wsp += (size_t)N * 4;
    int*   deg     = (int*)wsp;   wsp += (size_t)N * 4;
    int*   off     = (int*)wsp;   wsp += (size_t)N * 4;
    float* pcen    = (float*)wsp; wsp += (size_t)B * 4 * C * 4;

    // output layout (flat f32, reference return order)
    float* out     = (float*)d_out;
    float* o_xnew  = out;                                   // BK*C
    float* o_newei = o_xnew + (size_t)BK * C;               // 2E
    float* o_eattr = o_newei + 2 * (size_t)E;               // E
    float* o_mask  = o_eattr + (size_t)E;                   // E
    float* o_batch = o_mask + (size_t)E;                    // BK
    float* o_perm  = o_batch + (size_t)BK;                  // BK
    float* o_kl    = o_perm + (size_t)BK;                   // B
    float* o_ind   = o_kl + (size_t)B;                      // B*NPG

    // scratch aliased onto d_out (dead before those outputs are written)
    float* hbuf = out;                 // N*C floats (= o_xnew + o_newei region)
    int*   csr  = (int*)o_eattr;       // E ints
    float* wcsr = o_mask;              // E floats (per-edge dinv[src])

    hipMemsetAsync(mapping, 0xFF, (size_t)N * 4, stream);   // -1

    build_graph_k<<<B, 256, 0, stream>>>(ei, E, deg, dinv, off, csr, wcsr);
    gemm_k<<<(N + 511) / 512, 256, 0, stream>>>(x, W, hbuf, N);
    gather_k<<<(N + 3) / 4, 256, 0, stream>>>(csr, wcsr, off, deg, hbuf, dinv, bias, out2, N, B);
    centroid_part_k<<<B * 4, 256, 0, stream>>>(out2, pcen);
    cen_fin_k<<<B, 64, 0, stream>>>(pcen, cen, cnorm);
    score_k<<<(N + 255) / 256, 256, 0, stream>>>(out2, cen, cnorm, score, N);
    softmax_kl_k<<<B, 256, 0, stream>>>(score, o_kl);
    sort_k<<<B, 512, 0, stream>>>(score, sidx, o_ind);
    topk_k<<<(BK + 255) / 256, 256, 0, stream>>>(sidx, score, out2, mapping,
                                                 o_xnew, o_batch, o_perm, BK);
    edge_out_k<<<(E / 4 + 255) / 256, 256, 0, stream>>>(ei, eattr, mapping,
                                                        o_newei, o_eattr, o_mask, E);
}

// Round 2
// 491.670 us; speedup vs baseline: 1.0315x; 1.0063x over previous
//
#include <hip/hip_runtime.h>
#include <math.h>

#define NPG 1000
#define KTOP 500
#define C 64
#define EPG 16000   // edges per graph = NPG * DEG

__device__ __forceinline__ float readlane_f(float v, int l) {
    return __uint_as_float(__builtin_amdgcn_readlane(__float_as_uint(v), (unsigned)l));
}
__device__ __forceinline__ int readlane_i(int v, int l) {
    return (int)__builtin_amdgcn_readlane((unsigned)v, (unsigned)l);
}

// ---------------- fused per-graph CSR build: count + scan + scatter in LDS ----------------
// One block per graph. Edge list is graph-major: edges [g*EPG,(g+1)*EPG) belong to
// graph g and node ids lie in [g*NPG,(g+1)*NPG). All scatter traffic stays in LDS;
// global csr is written fully coalesced.
__global__ __launch_bounds__(256) void build_graph_k(const int* __restrict__ ei, int E,
                                                     int* __restrict__ deg,
                                                     float* __restrict__ dinv,
                                                     int* __restrict__ off,
                                                     int* __restrict__ csr) {
    int g = blockIdx.x, t = threadIdx.x;
    __shared__ int cnt[NPG];               // counts, then cursors
    __shared__ int soff[NPG];              // local start offsets
    __shared__ unsigned short lcsr[EPG];   // src local ids, dst-grouped
    __shared__ int red[256];
    const int gbase = g * NPG;
    const int ebase = g * EPG;
    const int* __restrict__ srcp = ei + ebase;
    const int* __restrict__ dstp = ei + E + ebase;

    for (int i = t; i < NPG; i += 256) cnt[i] = 0;
    __syncthreads();
    // phase 1: count in-degree (LDS atomics)
    for (int i = t; i < EPG; i += 256) atomicAdd(&cnt[dstp[i] - gbase], 1);
    __syncthreads();
    // phase 2: exclusive scan over 1000 counts (4 per thread + Hillis-Steele on 256)
    int base = t * 4;
    int v0 = 0, v1 = 0, v2 = 0, v3 = 0;
    if (base + 0 < NPG) v0 = cnt[base + 0];
    if (base + 1 < NPG) v1 = cnt[base + 1];
    if (base + 2 < NPG) v2 = cnt[base + 2];
    if (base + 3 < NPG) v3 = cnt[base + 3];
    int s = v0 + v1 + v2 + v3;
    red[t] = s;
    __syncthreads();
    for (int o = 1; o < 256; o <<= 1) {
        int xx = (t >= o) ? red[t - o] : 0;
        __syncthreads();
        red[t] += xx;
        __syncthreads();
    }
    int p = red[t] - s;                    // exclusive prefix
    if (base + 0 < NPG) { soff[base + 0] = p; p += v0; }
    if (base + 1 < NPG) { soff[base + 1] = p; p += v1; }
    if (base + 2 < NPG) { soff[base + 2] = p; p += v2; }
    if (base + 3 < NPG) { soff[base + 3] = p; p += v3; }
    __syncthreads();
    // outputs: deg, dinv, off (coalesced)
    for (int i = t; i < NPG; i += 256) {
        int d = cnt[i];
        deg[gbase + i] = d;
        dinv[gbase + i] = 1.0f / sqrtf((float)(d + 1));
        off[gbase + i] = ebase + soff[i];
    }
    __syncthreads();
    // reset cursors
    for (int i = t; i < NPG; i += 256) cnt[i] = soff[i];
    __syncthreads();
    // phase 3: scatter src into dst-grouped order (LDS cursor atomics + LDS writes)
    for (int i = t; i < EPG; i += 256) {
        int d = dstp[i] - gbase;
        int pos = atomicAdd(&cnt[d], 1);
        lcsr[pos] = (unsigned short)(srcp[i] - gbase);
    }
    __syncthreads();
    // phase 4: dump csr as coalesced int4 stores (EPG % 4 == 0)
    int4* co = (int4*)(csr + ebase);
    for (int i = t; i < EPG / 4; i += 256) {
        int4 v;
        v.x = gbase + (int)lcsr[i * 4 + 0];
        v.y = gbase + (int)lcsr[i * 4 + 1];
        v.z = gbase + (int)lcsr[i * 4 + 2];
        v.w = gbase + (int)lcsr[i * 4 + 3];
        co[i] = v;
    }
}

// ---------------- h2 = (x @ W) * dinv[row] : register-tiled, 2 rows/thread, W in LDS --------
// dinv folded into the GEMM epilogue so the gather loop needs NO per-edge weight:
// out[i] = bias + dinv[i]*(sum_{j->i} h2[j] + h2[i]).
__global__ __launch_bounds__(256) void gemm_k(const float* __restrict__ x,
                                              const float* __restrict__ W,
                                              const float* __restrict__ dinv,
                                              float* __restrict__ h2, int N) {
    __shared__ float sW[C * C];
    int t = threadIdx.x;
    for (int i = t; i < C * C / 4; i += 256) ((float4*)sW)[i] = ((const float4*)W)[i];
    __syncthreads();
    int r0 = blockIdx.x * 512 + t;
    int r1 = r0 + 256;
    if (r0 >= N) return;
    bool has1 = (r1 < N);
    const float4* x0 = (const float4*)(x + (size_t)r0 * C);
    const float4* x1 = (const float4*)(x + (size_t)(has1 ? r1 : r0) * C);
    float acc0[C], acc1[C];
#pragma unroll
    for (int i = 0; i < C; ++i) { acc0[i] = 0.f; acc1[i] = 0.f; }
    float4 a0 = x0[0], a1 = x1[0];
    for (int k4 = 0; k4 < 16; ++k4) {
        float4 b0, b1;
        if (k4 < 15) { b0 = x0[k4 + 1]; b1 = x1[k4 + 1]; }
        const float4* wr = (const float4*)(sW + k4 * 4 * C);
        const float* a0f = (const float*)&a0;
        const float* a1f = (const float*)&a1;
#pragma unroll
        for (int c4 = 0; c4 < 16; ++c4) {
            float4 w[4];
            w[0] = wr[c4]; w[1] = wr[16 + c4]; w[2] = wr[32 + c4]; w[3] = wr[48 + c4];
            const float* wf = (const float*)w;
#pragma unroll
            for (int j = 0; j < 4; ++j) {
                float s0 = acc0[c4 * 4 + j], s1 = acc1[c4 * 4 + j];
#pragma unroll
                for (int kk = 0; kk < 4; ++kk) {
                    float wv = wf[kk * 4 + j];
                    s0 = fmaf(a0f[kk], wv, s0);
                    s1 = fmaf(a1f[kk], wv, s1);
                }
                acc0[c4 * 4 + j] = s0; acc1[c4 * 4 + j] = s1;
            }
        }
        a0 = b0; a1 = b1;
    }
    float dv0 = dinv[r0];
    float dv1 = has1 ? dinv[r1] : 0.f;
#pragma unroll
    for (int i = 0; i < C; ++i) { acc0[i] *= dv0; acc1[i] *= dv1; }
    float4* h0 = (float4*)(h2 + (size_t)r0 * C);
#pragma unroll
    for (int q = 0; q < 16; ++q) h0[q] = ((float4*)acc0)[q];
    if (has1) {
        float4* h1 = (float4*)(h2 + (size_t)r1 * C);
#pragma unroll
        for (int q = 0; q < 16; ++q) h1[q] = ((float4*)acc1)[q];
    }
}

// ---------------- gather aggregation: one wave per node, lane = channel ----------------
// XCD-swizzled so each graph's h2 slice stays in one XCD's L2.
// Per edge: 1 readlane (uniform src -> SGPR) + 1 coalesced 256B row load + 1 add.
// No per-edge weight at all (folded into h2 by gemm_k).
__global__ __launch_bounds__(256) void gather_k(const int* __restrict__ csr,
                                                const int* __restrict__ off,
                                                const int* __restrict__ deg,
                                                const float* __restrict__ h2,
                                                const float* __restrict__ dinv,
                                                const float* __restrict__ bias,
                                                float* __restrict__ out2, int N, int B) {
    int b = blockIdx.x;
    int wave = threadIdx.x >> 6;
    int lane = threadIdx.x & 63;
    int node;
    if ((B & 7) == 0) {
        int xcd = b & 7, slot = b >> 3;
        int gpx = B >> 3;
        int g = xcd * gpx + slot / (NPG / 4);
        int blkin = slot % (NPG / 4);
        node = g * NPG + blkin * 4 + wave;
    } else {
        node = b * 4 + wave;
    }
    if (node >= N) return;
    int o0 = off[node], dg = deg[node];
    float di = dinv[node];
    float hv2 = h2[(size_t)node * C + lane];
    int sv = 0;
    if (lane < dg) sv = csr[o0 + lane];
    float acc = 0.f;
    int jmax = dg < 64 ? dg : 64;
    int j = 0;
    for (; j + 8 <= jmax; j += 8) {
        int s0 = readlane_i(sv, j + 0);
        int s1 = readlane_i(sv, j + 1);
        int s2 = readlane_i(sv, j + 2);
        int s3 = readlane_i(sv, j + 3);
        int s4 = readlane_i(sv, j + 4);
        int s5 = readlane_i(sv, j + 5);
        int s6 = readlane_i(sv, j + 6);
        int s7 = readlane_i(sv, j + 7);
        float v0 = h2[(size_t)s0 * C + lane];
        float v1 = h2[(size_t)s1 * C + lane];
        float v2 = h2[(size_t)s2 * C + lane];
        float v3 = h2[(size_t)s3 * C + lane];
        float v4 = h2[(size_t)s4 * C + lane];
        float v5 = h2[(size_t)s5 * C + lane];
        float v6 = h2[(size_t)s6 * C + lane];
        float v7 = h2[(size_t)s7 * C + lane];
        acc += ((v0 + v1) + (v2 + v3)) + ((v4 + v5) + (v6 + v7));
    }
    for (; j + 4 <= jmax; j += 4) {
        int s0 = readlane_i(sv, j + 0);
        int s1 = readlane_i(sv, j + 1);
        int s2 = readlane_i(sv, j + 2);
        int s3 = readlane_i(sv, j + 3);
        float v0 = h2[(size_t)s0 * C + lane];
        float v1 = h2[(size_t)s1 * C + lane];
        float v2 = h2[(size_t)s2 * C + lane];
        float v3 = h2[(size_t)s3 * C + lane];
        acc += (v0 + v1) + (v2 + v3);
    }
    for (; j < jmax; ++j) {
        int s = readlane_i(sv, j);
        acc += h2[(size_t)s * C + lane];
    }
    for (; j < dg; ++j) {          // deg > 64 fallback (astronomically rare)
        int s = csr[o0 + j];
        acc += h2[(size_t)s * C + lane];
    }
    out2[(size_t)node * C + lane] = bias[lane] + di * (acc + hv2);
}

// ---------------- per-graph centroid: partial sums (4 blocks/graph) + finalize ----------------
__global__ void centroid_part_k(const float* __restrict__ out2, float* __restrict__ pcen) {
    int blk = blockIdx.x;
    int g = blk >> 2, p = blk & 3;
    int t = threadIdx.x;
    int c = t & 63, q = t >> 6;
    const float* base = out2 + (size_t)g * NPG * C;
    int n0 = p * 250, n1 = n0 + 250;
    float acc = 0.f;
    for (int n = n0 + q; n < n1; n += 4) acc += base[(size_t)n * C + c];
    __shared__ float red[256];
    red[t] = acc;
    __syncthreads();
    if (t < 64) pcen[(size_t)blk * C + t] = red[t] + red[64 + t] + red[128 + t] + red[192 + t];
}

__global__ void cen_fin_k(const float* __restrict__ pcen, float* __restrict__ cen,
                          float* __restrict__ cnorm) {
    int g = blockIdx.x, c = threadIdx.x;   // 64 threads
    float s = pcen[(size_t)(g * 4 + 0) * C + c] + pcen[(size_t)(g * 4 + 1) * C + c]
            + pcen[(size_t)(g * 4 + 2) * C + c] + pcen[(size_t)(g * 4 + 3) * C + c];
    float m = s / 1000.0f;
    cen[g * C + c] = m;
    float v = m * m;
    for (int o = 32; o > 0; o >>= 1) v += __shfl_down(v, o, 64);
    if (c == 0) cnorm[g] = sqrtf(v);
}

// cosine similarity of each node row vs its graph centroid
__global__ void score_k(const float* __restrict__ out2, const float* __restrict__ cen,
                        const float* __restrict__ cnorm, float* __restrict__ score, int N) {
    int i = blockIdx.x * 256 + threadIdx.x;
    if (i < N) {
        int g = i / NPG;
        const float4* xr = (const float4*)(out2 + (size_t)i * C);
        const float4* cr = (const float4*)(cen + g * C);
        float num = 0.f, sq = 0.f;
#pragma unroll
        for (int q = 0; q < 16; ++q) {
            float4 a = xr[q], b = cr[q];
            num += a.x * b.x + a.y * b.y + a.z * b.z + a.w * b.w;
            sq  += a.x * a.x + a.y * a.y + a.z * a.z + a.w * a.w;
        }
        float den = sqrtf(sq) * cnorm[g] + 1e-8f;
        score[i] = num / den;
    }
}

// per-graph KL(softmax || uniform) — score row staged in LDS (one global pass)
__global__ void softmax_kl_k(const float* __restrict__ score, float* __restrict__ o_kl) {
    int g = blockIdx.x, t = threadIdx.x;
    __shared__ float ss[NPG];
    __shared__ float red[256];
    const float4* s4 = (const float4*)(score + (size_t)g * NPG);
    for (int i = t; i < NPG / 4; i += 256) ((float4*)ss)[i] = s4[i];
    __syncthreads();
    float mx = -INFINITY;
    for (int i = t; i < NPG; i += 256) mx = fmaxf(mx, ss[i]);
    red[t] = mx;
    __syncthreads();
    for (int w = 128; w > 0; w >>= 1) { if (t < w) red[t] = fmaxf(red[t], red[t + w]); __syncthreads(); }
    mx = red[0];
    __syncthreads();
    float se = 0.f;
    for (int i = t; i < NPG; i += 256) se += expf(ss[i] - mx);
    red[t] = se;
    __syncthreads();
    for (int w = 128; w > 0; w >>= 1) { if (t < w) red[t] += red[t + w]; __syncthreads(); }
    float lse = logf(red[0]);
    __syncthreads();
    float kl = 0.f;
    const float ln_npg = 6.9077552790f;
    for (int i = t; i < NPG; i += 256) {
        float lp = ss[i] - mx - lse;
        kl += expf(lp) * (lp + ln_npg);
    }
    red[t] = kl;
    __syncthreads();
    for (int w = 128; w > 0; w >>= 1) { if (t < w) red[t] += red[t + w]; __syncthreads(); }
    if (t == 0) o_kl[g] = red[0];
}

// ---------------- per-graph full descending stable argsort (bitonic, 1024) ----------------
__global__ void sort_k(const float* __restrict__ score, int* __restrict__ sidx,
                       float* __restrict__ o_ind) {
    __shared__ unsigned long long kk[1024];
    int g = blockIdx.x, t = threadIdx.x;          // 512 threads
    for (int i = t; i < 1024; i += 512) {
        unsigned long long v;
        if (i < NPG) {
            unsigned u = __float_as_uint(score[(size_t)g * NPG + i]);
            u = (u & 0x80000000u) ? ~u : (u | 0x80000000u);
            v = ((unsigned long long)(~u) << 32) | (unsigned)i;
        } else {
            v = ~0ULL;
        }
        kk[i] = v;
    }
    __syncthreads();
    for (int k = 2; k <= 1024; k <<= 1) {
        for (int j = k >> 1; j > 0; j >>= 1) {
            for (int i = t; i < 1024; i += 512) {
                int ixj = i ^ j;
                if (ixj > i) {
                    unsigned long long a = kk[i], b = kk[ixj];
                    bool up = ((i & k) == 0);
                    if ((a > b) == up) { kk[i] = b; kk[ixj] = a; }
                }
            }
            __syncthreads();
        }
    }
    for (int i = t; i < NPG; i += 512) {
        int idx = (int)(kk[i] & 0xFFFFFFFFULL);
        sidx[(size_t)g * NPG + i] = idx;
        o_ind[(size_t)g * NPG + i] = (float)idx;
    }
}

// ---------------- top-K gather: x_new, perm, batch_new, mapping ----------------
__global__ void topk_k(const int* __restrict__ sidx, const float* __restrict__ score,
                       const float* __restrict__ out2, int* __restrict__ mapping,
                       float* __restrict__ o_xnew, float* __restrict__ o_batch,
                       float* __restrict__ o_perm, int BK) {
    int j = blockIdx.x * 256 + threadIdx.x;
    if (j < BK) {
        int b = j / KTOP, r = j - b * KTOP;
        int node = sidx[(size_t)b * NPG + r];
        int gn = b * NPG + node;
        mapping[gn] = j;
        o_perm[j] = (float)gn;
        o_batch[j] = (float)b;
        float tn = tanhf(score[gn]);
        const float4* src = (const float4*)(out2 + (size_t)gn * C);
        float4* dst = (float4*)(o_xnew + (size_t)j * C);
#pragma unroll
        for (int q = 0; q < 16; ++q) {
            float4 v = src[q];
            v.x *= tn; v.y *= tn; v.z *= tn; v.w *= tn;
            dst[q] = v;
        }
    }
}

// ---------------- edge re-index + mask + attr (x4 vectorized; E % 4 == 0) ----------------
__global__ void edge_out_k(const int* __restrict__ ei, const float* __restrict__ eattr,
                           const int* __restrict__ mapping, float* __restrict__ o_newei,
                           float* __restrict__ o_eattr, float* __restrict__ o_mask, int E) {
    int e4 = blockIdx.x * 256 + threadIdx.x;
    int q = E >> 2;
    if (e4 < q) {
        int4 sidx = ((const int4*)ei)[e4];
        int4 didx = ((const int4*)ei)[q + e4];
        int a0 = mapping[sidx.x], a1 = mapping[sidx.y], a2 = mapping[sidx.z], a3 = mapping[sidx.w];
        int b0 = mapping[didx.x], b1 = mapping[didx.y], b2 = mapping[didx.z], b3 = mapping[didx.w];
        float4 f0 = { (float)a0, (float)a1, (float)a2, (float)a3 };
        float4 f1 = { (float)b0, (float)b1, (float)b2, (float)b3 };
        ((float4*)o_newei)[e4] = f0;
        ((float4*)o_newei)[q + e4] = f1;
        float4 at = ((const float4*)eattr)[e4];
        float4 mk, ea;
        mk.x = (a0 >= 0 && b0 >= 0) ? 1.0f : 0.0f;
        mk.y = (a1 >= 0 && b1 >= 0) ? 1.0f : 0.0f;
        mk.z = (a2 >= 0 && b2 >= 0) ? 1.0f : 0.0f;
        mk.w = (a3 >= 0 && b3 >= 0) ? 1.0f : 0.0f;
        ea.x = mk.x != 0.0f ? at.x : 0.0f;
        ea.y = mk.y != 0.0f ? at.y : 0.0f;
        ea.z = mk.z != 0.0f ? at.z : 0.0f;
        ea.w = mk.w != 0.0f ? at.w : 0.0f;
        ((float4*)o_mask)[e4] = mk;
        ((float4*)o_eattr)[e4] = ea;
    }
}

extern "C" void kernel_launch(void* const* d_in, const int* in_sizes, int n_in,
                              void* d_out, int out_size, void* d_ws, size_t ws_size,
                              hipStream_t stream) {
    (void)n_in; (void)out_size; (void)ws_size;
    const float* x     = (const float*)d_in[1];
    const int*   ei    = (const int*)d_in[2];
    const float* eattr = (const float*)d_in[3];
    const float* W     = (const float*)d_in[5];
    const float* bias  = (const float*)d_in[6];

    const int N  = in_sizes[1] / C;    // 256000
    const int E  = in_sizes[2] / 2;    // 4096000
    const int B  = N / NPG;            // 256
    const int BK = B * KTOP;           // 128000

    // workspace layout
    char* wsp = (char*)d_ws;
    float* out2    = (float*)wsp; wsp += (size_t)N * C * 4;   // 65.5 MB
    float* dinv    = (float*)wsp; wsp += (size_t)N * 4;
    float* score   = (float*)wsp; wsp += (size_t)N * 4;
    float* cen     = (float*)wsp; wsp += (size_t)B * C * 4;
    float* cnorm   = (float*)wsp; wsp += 1024;
    int*   sidx    = (int*)wsp;   wsp += (size_t)B * NPG * 4;
    int*   mapping = (int*)wsp;   wsp += (size_t)N * 4;
    int*   deg     = (int*)wsp;   wsp += (size_t)N * 4;
    int*   off     = (int*)wsp;   wsp += (size_t)N * 4;
    float* pcen    = (float*)wsp; wsp += (size_t)B * 4 * C * 4;

    // output layout (flat f32, reference return order)
    float* out     = (float*)d_out;
    float* o_xnew  = out;                                   // BK*C
    float* o_newei = o_xnew + (size_t)BK * C;               // 2E
    float* o_eattr = o_newei + 2 * (size_t)E;               // E
    float* o_mask  = o_eattr + (size_t)E;                   // E
    float* o_batch = o_mask + (size_t)E;                    // BK
    float* o_perm  = o_batch + (size_t)BK;                  // BK
    float* o_kl    = o_perm + (size_t)BK;                   // B
    float* o_ind   = o_kl + (size_t)B;                      // B*NPG

    // scratch aliased onto d_out (dead before those outputs are written)
    float* h2buf = out;                // N*C floats (= o_xnew + o_newei region)
    int*   csr   = (int*)o_eattr;      // E ints

    hipMemsetAsync(mapping, 0xFF, (size_t)N * 4, stream);   // -1

    build_graph_k<<<B, 256, 0, stream>>>(ei, E, deg, dinv, off, csr);
    gemm_k<<<(N + 511) / 512, 256, 0, stream>>>(x, W, dinv, h2buf, N);
    gather_k<<<(N + 3) / 4, 256, 0, stream>>>(csr, off, deg, h2buf, dinv, bias, out2, N, B);
    centroid_part_k<<<B * 4, 256, 0, stream>>>(out2, pcen);
    cen_fin_k<<<B, 64, 0, stream>>>(pcen, cen, cnorm);
    score_k<<<(N + 255) / 256, 256, 0, stream>>>(out2, cen, cnorm, score, N);
    softmax_kl_k<<<B, 256, 0, stream>>>(score, o_kl);
    sort_k<<<B, 512, 0, stream>>>(score, sidx, o_ind);
    topk_k<<<(BK + 255) / 256, 256, 0, stream>>>(sidx, score, out2, mapping,
                                                 o_xnew, o_batch, o_perm, BK);
    edge_out_k<<<(E / 4 + 255) / 256, 256, 0, stream>>>(ei, eattr, mapping,
                                                        o_newei, o_eattr, o_mask, E);
}

// Round 3
// 397.876 us; speedup vs baseline: 1.2747x; 1.2357x over previous
//
#include <hip/hip_runtime.h>
#include <math.h>

#define NPG 1000
#define KTOP 500
#define C 64
#define EPG 16000   // edges per graph = NPG * DEG
#define BPG 63      // gather blocks per graph: ceil(250/4), 4 bases/block, 4 nodes/base-wave

__device__ __forceinline__ float readlane_f(float v, int l) {
    return __uint_as_float(__builtin_amdgcn_readlane(__float_as_uint(v), (unsigned)l));
}
__device__ __forceinline__ int readlane_i(int v, int l) {
    return (int)__builtin_amdgcn_readlane((unsigned)v, (unsigned)l);
}

// ---------------- fused per-graph CSR build: count + scan + scatter in LDS ----------------
// 1024 threads (16 waves/CU at grid==B==CU-count) for latency hiding on the edge scans.
__global__ __launch_bounds__(1024) void build_graph_k(const int* __restrict__ ei, int E,
                                                      int* __restrict__ deg,
                                                      float* __restrict__ dinv,
                                                      int* __restrict__ off,
                                                      int* __restrict__ csr) {
    int g = blockIdx.x, t = threadIdx.x;
    __shared__ int cnt[NPG];               // counts, then cursors
    __shared__ int soff[NPG];              // local start offsets
    __shared__ unsigned short lcsr[EPG];   // src local ids, dst-grouped
    __shared__ int red[1024];
    const int gbase = g * NPG;
    const int ebase = g * EPG;
    const int* __restrict__ srcp = ei + ebase;
    const int* __restrict__ dstp = ei + E + ebase;

    for (int i = t; i < NPG; i += 1024) cnt[i] = 0;
    __syncthreads();
    // phase 1: count in-degree (LDS atomics)
    for (int i = t; i < EPG; i += 1024) atomicAdd(&cnt[dstp[i] - gbase], 1);
    __syncthreads();
    // phase 2: exclusive scan over 1000 counts (1/thread, Hillis-Steele on 1024)
    int v = (t < NPG) ? cnt[t] : 0;
    red[t] = v;
    __syncthreads();
    for (int o = 1; o < 1024; o <<= 1) {
        int xx = (t >= o) ? red[t - o] : 0;
        __syncthreads();
        red[t] += xx;
        __syncthreads();
    }
    if (t < NPG) soff[t] = red[t] - v;     // exclusive prefix
    __syncthreads();
    // outputs: deg, dinv, off (coalesced)
    for (int i = t; i < NPG; i += 1024) {
        int d = cnt[i];
        deg[gbase + i] = d;
        dinv[gbase + i] = 1.0f / sqrtf((float)(d + 1));
        off[gbase + i] = ebase + soff[i];
    }
    __syncthreads();
    // reset cursors
    for (int i = t; i < NPG; i += 1024) cnt[i] = soff[i];
    __syncthreads();
    // phase 3: scatter src into dst-grouped order (LDS cursor atomics + LDS writes)
    for (int i = t; i < EPG; i += 1024) {
        int d = dstp[i] - gbase;
        int pos = atomicAdd(&cnt[d], 1);
        lcsr[pos] = (unsigned short)(srcp[i] - gbase);
    }
    __syncthreads();
    // phase 4: dump csr as coalesced int4 stores (EPG % 4 == 0)
    int4* co = (int4*)(csr + ebase);
    for (int i = t; i < EPG / 4; i += 1024) {
        int4 vv;
        vv.x = gbase + (int)lcsr[i * 4 + 0];
        vv.y = gbase + (int)lcsr[i * 4 + 1];
        vv.z = gbase + (int)lcsr[i * 4 + 2];
        vv.w = gbase + (int)lcsr[i * 4 + 3];
        co[i] = vv;
    }
}

// ---------------- h2 = (x @ W) * dinv[row] : register-tiled, 2 rows/thread, W in LDS --------
__global__ __launch_bounds__(256) void gemm_k(const float* __restrict__ x,
                                              const float* __restrict__ W,
                                              const float* __restrict__ dinv,
                                              float* __restrict__ h2, int N) {
    __shared__ float sW[C * C];
    int t = threadIdx.x;
    for (int i = t; i < C * C / 4; i += 256) ((float4*)sW)[i] = ((const float4*)W)[i];
    __syncthreads();
    int r0 = blockIdx.x * 512 + t;
    int r1 = r0 + 256;
    if (r0 >= N) return;
    bool has1 = (r1 < N);
    const float4* x0 = (const float4*)(x + (size_t)r0 * C);
    const float4* x1 = (const float4*)(x + (size_t)(has1 ? r1 : r0) * C);
    float acc0[C], acc1[C];
#pragma unroll
    for (int i = 0; i < C; ++i) { acc0[i] = 0.f; acc1[i] = 0.f; }
    float4 a0 = x0[0], a1 = x1[0];
    for (int k4 = 0; k4 < 16; ++k4) {
        float4 b0, b1;
        if (k4 < 15) { b0 = x0[k4 + 1]; b1 = x1[k4 + 1]; }
        const float4* wr = (const float4*)(sW + k4 * 4 * C);
        const float* a0f = (const float*)&a0;
        const float* a1f = (const float*)&a1;
#pragma unroll
        for (int c4 = 0; c4 < 16; ++c4) {
            float4 w[4];
            w[0] = wr[c4]; w[1] = wr[16 + c4]; w[2] = wr[32 + c4]; w[3] = wr[48 + c4];
            const float* wf = (const float*)w;
#pragma unroll
            for (int j = 0; j < 4; ++j) {
                float s0 = acc0[c4 * 4 + j], s1 = acc1[c4 * 4 + j];
#pragma unroll
                for (int kk = 0; kk < 4; ++kk) {
                    float wv = wf[kk * 4 + j];
                    s0 = fmaf(a0f[kk], wv, s0);
                    s1 = fmaf(a1f[kk], wv, s1);
                }
                acc0[c4 * 4 + j] = s0; acc1[c4 * 4 + j] = s1;
            }
        }
        a0 = b0; a1 = b1;
    }
    float dv0 = dinv[r0];
    float dv1 = has1 ? dinv[r1] : 0.f;
#pragma unroll
    for (int i = 0; i < C; ++i) { acc0[i] *= dv0; acc1[i] *= dv1; }
    float4* h0 = (float4*)(h2 + (size_t)r0 * C);
#pragma unroll
    for (int q = 0; q < 16; ++q) h0[q] = ((float4*)acc0)[q];
    if (has1) {
        float4* h1 = (float4*)(h2 + (size_t)r1 * C);
#pragma unroll
        for (int q = 0; q < 16; ++q) h1[q] = ((float4*)acc1)[q];
    }
}

// ---------------- gather aggregation: 4 nodes per wave, lane = channel -----------------
// Latency-bound fix: 4 independent gather chains per wave (nodes n, n+250, n+500, n+750
// of the same graph). Neighbor slots beyond deg are padded with the node's OWN id and
// compensated in the epilogue (coef = 1 - padcount folded into the self-term fma), so the
// inner loop is a single branch-free uniform loop issuing 16 independent loads per step.
// Per-graph centroid partial sums fused in: LDS accumulate + 1 global atomic per block.
__global__ __launch_bounds__(256) void gather_k(const int* __restrict__ csr,
                                                const int* __restrict__ off,
                                                const int* __restrict__ deg,
                                                const float* __restrict__ h2,
                                                const float* __restrict__ dinv,
                                                const float* __restrict__ bias,
                                                float* __restrict__ out2,
                                                float* __restrict__ cen_sum,
                                                int N, int B) {
    __shared__ float cenacc[C];
    int blk = blockIdx.x;
    int wave = threadIdx.x >> 6;
    int lane = threadIdx.x & 63;
    int t = threadIdx.x;
    int g, blkin;
    if ((B & 7) == 0) {                    // XCD swizzle: whole graph on one XCD
        int xcd = blk & 7, slot = blk >> 3;
        g = (slot / BPG) * 8 + xcd;
        blkin = slot % BPG;
    } else {
        g = blk / BPG;
        blkin = blk % BPG;
    }
    if (t < C) cenacc[t] = 0.f;
    __syncthreads();

    int base = blkin * 4 + wave;
    bool active = (base < NPG / 4);
    float csum = 0.f;
    if (active) {
        int nA = g * NPG + base;
        int nB = nA + 250, nC = nA + 500, nD = nA + 750;
        int oA = off[nA], oB = off[nB], oC = off[nC], oD = off[nD];
        int dA = deg[nA], dB = deg[nB], dC = deg[nC], dD = deg[nD];
        float diA = dinv[nA], diB = dinv[nB], diC = dinv[nC], diD = dinv[nD];
        float hA = h2[(size_t)nA * C + lane];
        float hB = h2[(size_t)nB * C + lane];
        float hC = h2[(size_t)nC * C + lane];
        float hD = h2[(size_t)nD * C + lane];
        float bv = bias[lane];
        // neighbor id vectors, padded with own node id
        int svA = (lane < dA) ? csr[oA + lane] : nA;
        int svB = (lane < dB) ? csr[oB + lane] : nB;
        int svC = (lane < dC) ? csr[oC + lane] : nC;
        int svD = (lane < dD) ? csr[oD + lane] : nD;
        int jmA = dA < 64 ? dA : 64;
        int jmB = dB < 64 ? dB : 64;
        int jmC = dC < 64 ? dC : 64;
        int jmD = dD < 64 ? dD : 64;
        int rA = (jmA + 3) & ~3, rB = (jmB + 3) & ~3;
        int rC = (jmC + 3) & ~3, rD = (jmD + 3) & ~3;
        int m0 = rA > rB ? rA : rB;
        int m1 = rC > rD ? rC : rD;
        int mmax = m0 > m1 ? m0 : m1;
        float aA = 0.f, aB = 0.f, aC = 0.f, aD = 0.f;
        for (int j = 0; j < mmax; j += 4) {
            int sA0 = readlane_i(svA, j + 0), sA1 = readlane_i(svA, j + 1);
            int sA2 = readlane_i(svA, j + 2), sA3 = readlane_i(svA, j + 3);
            int sB0 = readlane_i(svB, j + 0), sB1 = readlane_i(svB, j + 1);
            int sB2 = readlane_i(svB, j + 2), sB3 = readlane_i(svB, j + 3);
            int sC0 = readlane_i(svC, j + 0), sC1 = readlane_i(svC, j + 1);
            int sC2 = readlane_i(svC, j + 2), sC3 = readlane_i(svC, j + 3);
            int sD0 = readlane_i(svD, j + 0), sD1 = readlane_i(svD, j + 1);
            int sD2 = readlane_i(svD, j + 2), sD3 = readlane_i(svD, j + 3);
            float vA0 = h2[(size_t)sA0 * C + lane];
            float vA1 = h2[(size_t)sA1 * C + lane];
            float vA2 = h2[(size_t)sA2 * C + lane];
            float vA3 = h2[(size_t)sA3 * C + lane];
            float vB0 = h2[(size_t)sB0 * C + lane];
            float vB1 = h2[(size_t)sB1 * C + lane];
            float vB2 = h2[(size_t)sB2 * C + lane];
            float vB3 = h2[(size_t)sB3 * C + lane];
            float vC0 = h2[(size_t)sC0 * C + lane];
            float vC1 = h2[(size_t)sC1 * C + lane];
            float vC2 = h2[(size_t)sC2 * C + lane];
            float vC3 = h2[(size_t)sC3 * C + lane];
            float vD0 = h2[(size_t)sD0 * C + lane];
            float vD1 = h2[(size_t)sD1 * C + lane];
            float vD2 = h2[(size_t)sD2 * C + lane];
            float vD3 = h2[(size_t)sD3 * C + lane];
            aA += (vA0 + vA1) + (vA2 + vA3);
            aB += (vB0 + vB1) + (vB2 + vB3);
            aC += (vC0 + vC1) + (vC2 + vC3);
            aD += (vD0 + vD1) + (vD2 + vD3);
        }
        // deg > 64 fallback (essentially never: Poisson(16))
        for (int j = 64; j < dA; ++j) aA += h2[(size_t)csr[oA + j] * C + lane];
        for (int j = 64; j < dB; ++j) aB += h2[(size_t)csr[oB + j] * C + lane];
        for (int j = 64; j < dC; ++j) aC += h2[(size_t)csr[oC + j] * C + lane];
        for (int j = 64; j < dD; ++j) aD += h2[(size_t)csr[oD + j] * C + lane];
        // pad compensation: acc holds (mmax - jm) extra copies of own row; want exactly +1
        float cA = 1.0f - (float)(mmax - jmA);
        float cB = 1.0f - (float)(mmax - jmB);
        float cC = 1.0f - (float)(mmax - jmC);
        float cD = 1.0f - (float)(mmax - jmD);
        float resA = fmaf(diA, fmaf(cA, hA, aA), bv);
        float resB = fmaf(diB, fmaf(cB, hB, aB), bv);
        float resC = fmaf(diC, fmaf(cC, hC, aC), bv);
        float resD = fmaf(diD, fmaf(cD, hD, aD), bv);
        out2[(size_t)nA * C + lane] = resA;
        out2[(size_t)nB * C + lane] = resB;
        out2[(size_t)nC * C + lane] = resC;
        out2[(size_t)nD * C + lane] = resD;
        csum = (resA + resB) + (resC + resD);
        atomicAdd(&cenacc[lane], csum);
    }
    __syncthreads();
    if (t < C) atomicAdd(&cen_sum[(size_t)g * C + t], cenacc[t]);
}

__global__ void cen_fin_k(const float* __restrict__ cen_sum, float* __restrict__ cen,
                          float* __restrict__ cnorm) {
    int g = blockIdx.x, c = threadIdx.x;   // 64 threads
    float m = cen_sum[(size_t)g * C + c] / 1000.0f;
    cen[g * C + c] = m;
    float v = m * m;
    for (int o = 32; o > 0; o >>= 1) v += __shfl_down(v, o, 64);
    if (c == 0) cnorm[g] = sqrtf(v);
}

// cosine similarity of each node row vs its graph centroid
__global__ void score_k(const float* __restrict__ out2, const float* __restrict__ cen,
                        const float* __restrict__ cnorm, float* __restrict__ score, int N) {
    int i = blockIdx.x * 256 + threadIdx.x;
    if (i < N) {
        int g = i / NPG;
        const float4* xr = (const float4*)(out2 + (size_t)i * C);
        const float4* cr = (const float4*)(cen + g * C);
        float num = 0.f, sq = 0.f;
#pragma unroll
        for (int q = 0; q < 16; ++q) {
            float4 a = xr[q], b = cr[q];
            num += a.x * b.x + a.y * b.y + a.z * b.z + a.w * b.w;
            sq  += a.x * a.x + a.y * a.y + a.z * a.z + a.w * a.w;
        }
        float den = sqrtf(sq) * cnorm[g] + 1e-8f;
        score[i] = num / den;
    }
}

// per-graph KL(softmax || uniform) — score row staged in LDS (one global pass)
__global__ void softmax_kl_k(const float* __restrict__ score, float* __restrict__ o_kl) {
    int g = blockIdx.x, t = threadIdx.x;
    __shared__ float ss[NPG];
    __shared__ float red[256];
    const float4* s4 = (const float4*)(score + (size_t)g * NPG);
    for (int i = t; i < NPG / 4; i += 256) ((float4*)ss)[i] = s4[i];
    __syncthreads();
    float mx = -INFINITY;
    for (int i = t; i < NPG; i += 256) mx = fmaxf(mx, ss[i]);
    red[t] = mx;
    __syncthreads();
    for (int w = 128; w > 0; w >>= 1) { if (t < w) red[t] = fmaxf(red[t], red[t + w]); __syncthreads(); }
    mx = red[0];
    __syncthreads();
    float se = 0.f;
    for (int i = t; i < NPG; i += 256) se += expf(ss[i] - mx);
    red[t] = se;
    __syncthreads();
    for (int w = 128; w > 0; w >>= 1) { if (t < w) red[t] += red[t + w]; __syncthreads(); }
    float lse = logf(red[0]);
    __syncthreads();
    float kl = 0.f;
    const float ln_npg = 6.9077552790f;
    for (int i = t; i < NPG; i += 256) {
        float lp = ss[i] - mx - lse;
        kl += expf(lp) * (lp + ln_npg);
    }
    red[t] = kl;
    __syncthreads();
    for (int w = 128; w > 0; w >>= 1) { if (t < w) red[t] += red[t + w]; __syncthreads(); }
    if (t == 0) o_kl[g] = red[0];
}

// ---------------- per-graph full descending stable argsort (bitonic, 1024 thr) -------------
__global__ __launch_bounds__(1024) void sort_k(const float* __restrict__ score,
                                               int* __restrict__ sidx,
                                               float* __restrict__ o_ind) {
    __shared__ unsigned long long kk[1024];
    int g = blockIdx.x, t = threadIdx.x;          // 1024 threads, 1 element each
    unsigned long long v;
    if (t < NPG) {
        unsigned u = __float_as_uint(score[(size_t)g * NPG + t]);
        u = (u & 0x80000000u) ? ~u : (u | 0x80000000u);
        v = ((unsigned long long)(~u) << 32) | (unsigned)t;
    } else {
        v = ~0ULL;
    }
    kk[t] = v;
    __syncthreads();
    for (int k = 2; k <= 1024; k <<= 1) {
        for (int j = k >> 1; j > 0; j >>= 1) {
            int ixj = t ^ j;
            if (ixj > t) {
                unsigned long long a = kk[t], b = kk[ixj];
                bool up = ((t & k) == 0);
                if ((a > b) == up) { kk[t] = b; kk[ixj] = a; }
            }
            __syncthreads();
        }
    }
    if (t < NPG) {
        int idx = (int)(kk[t] & 0xFFFFFFFFULL);
        sidx[(size_t)g * NPG + t] = idx;
        o_ind[(size_t)g * NPG + t] = (float)idx;
    }
}

// ---------------- top-K gather: x_new, perm, batch_new, mapping ----------------
__global__ void topk_k(const int* __restrict__ sidx, const float* __restrict__ score,
                       const float* __restrict__ out2, int* __restrict__ mapping,
                       float* __restrict__ o_xnew, float* __restrict__ o_batch,
                       float* __restrict__ o_perm, int BK) {
    int j = blockIdx.x * 256 + threadIdx.x;
    if (j < BK) {
        int b = j / KTOP, r = j - b * KTOP;
        int node = sidx[(size_t)b * NPG + r];
        int gn = b * NPG + node;
        mapping[gn] = j;
        o_perm[j] = (float)gn;
        o_batch[j] = (float)b;
        float tn = tanhf(score[gn]);
        const float4* src = (const float4*)(out2 + (size_t)gn * C);
        float4* dst = (float4*)(o_xnew + (size_t)j * C);
#pragma unroll
        for (int q = 0; q < 16; ++q) {
            float4 v = src[q];
            v.x *= tn; v.y *= tn; v.z *= tn; v.w *= tn;
            dst[q] = v;
        }
    }
}

// ---------------- edge re-index + mask + attr (x4 vectorized; E % 4 == 0) ----------------
__global__ void edge_out_k(const int* __restrict__ ei, const float* __restrict__ eattr,
                           const int* __restrict__ mapping, float* __restrict__ o_newei,
                           float* __restrict__ o_eattr, float* __restrict__ o_mask, int E) {
    int e4 = blockIdx.x * 256 + threadIdx.x;
    int q = E >> 2;
    if (e4 < q) {
        int4 sidx = ((const int4*)ei)[e4];
        int4 didx = ((const int4*)ei)[q + e4];
        int a0 = mapping[sidx.x], a1 = mapping[sidx.y], a2 = mapping[sidx.z], a3 = mapping[sidx.w];
        int b0 = mapping[didx.x], b1 = mapping[didx.y], b2 = mapping[didx.z], b3 = mapping[didx.w];
        float4 f0 = { (float)a0, (float)a1, (float)a2, (float)a3 };
        float4 f1 = { (float)b0, (float)b1, (float)b2, (float)b3 };
        ((float4*)o_newei)[e4] = f0;
        ((float4*)o_newei)[q + e4] = f1;
        float4 at = ((const float4*)eattr)[e4];
        float4 mk, ea;
        mk.x = (a0 >= 0 && b0 >= 0) ? 1.0f : 0.0f;
        mk.y = (a1 >= 0 && b1 >= 0) ? 1.0f : 0.0f;
        mk.z = (a2 >= 0 && b2 >= 0) ? 1.0f : 0.0f;
        mk.w = (a3 >= 0 && b3 >= 0) ? 1.0f : 0.0f;
        ea.x = mk.x != 0.0f ? at.x : 0.0f;
        ea.y = mk.y != 0.0f ? at.y : 0.0f;
        ea.z = mk.z != 0.0f ? at.z : 0.0f;
        ea.w = mk.w != 0.0f ? at.w : 0.0f;
        ((float4*)o_mask)[e4] = mk;
        ((float4*)o_eattr)[e4] = ea;
    }
}

extern "C" void kernel_launch(void* const* d_in, const int* in_sizes, int n_in,
                              void* d_out, int out_size, void* d_ws, size_t ws_size,
                              hipStream_t stream) {
    (void)n_in; (void)out_size; (void)ws_size;
    const float* x     = (const float*)d_in[1];
    const int*   ei    = (const int*)d_in[2];
    const float* eattr = (const float*)d_in[3];
    const float* W     = (const float*)d_in[5];
    const float* bias  = (const float*)d_in[6];

    const int N  = in_sizes[1] / C;    // 256000
    const int E  = in_sizes[2] / 2;    // 4096000
    const int B  = N / NPG;            // 256
    const int BK = B * KTOP;           // 128000

    // workspace layout
    char* wsp = (char*)d_ws;
    float* out2    = (float*)wsp; wsp += (size_t)N * C * 4;   // 65.5 MB
    float* dinv    = (float*)wsp; wsp += (size_t)N * 4;
    float* score   = (float*)wsp; wsp += (size_t)N * 4;
    float* cen     = (float*)wsp; wsp += (size_t)B * C * 4;
    float* cnorm   = (float*)wsp; wsp += 1024;
    int*   sidx    = (int*)wsp;   wsp += (size_t)B * NPG * 4;
    int*   mapping = (int*)wsp;   wsp += (size_t)N * 4;
    int*   deg     = (int*)wsp;   wsp += (size_t)N * 4;
    int*   off     = (int*)wsp;   wsp += (size_t)N * 4;
    float* cen_sum = (float*)wsp; wsp += (size_t)B * C * 4;

    // output layout (flat f32, reference return order)
    float* out     = (float*)d_out;
    float* o_xnew  = out;                                   // BK*C
    float* o_newei = o_xnew + (size_t)BK * C;               // 2E
    float* o_eattr = o_newei + 2 * (size_t)E;               // E
    float* o_mask  = o_eattr + (size_t)E;                   // E
    float* o_batch = o_mask + (size_t)E;                    // BK
    float* o_perm  = o_batch + (size_t)BK;                  // BK
    float* o_kl    = o_perm + (size_t)BK;                   // B
    float* o_ind   = o_kl + (size_t)B;                      // B*NPG

    // scratch aliased onto d_out (dead before those outputs are written)
    float* h2buf = out;                // N*C floats (= o_xnew + o_newei region)
    int*   csr   = (int*)o_eattr;      // E ints

    hipMemsetAsync(mapping, 0xFF, (size_t)N * 4, stream);   // -1
    hipMemsetAsync(cen_sum, 0, (size_t)B * C * 4, stream);

    build_graph_k<<<B, 1024, 0, stream>>>(ei, E, deg, dinv, off, csr);
    gemm_k<<<(N + 511) / 512, 256, 0, stream>>>(x, W, dinv, h2buf, N);
    gather_k<<<B * BPG, 256, 0, stream>>>(csr, off, deg, h2buf, dinv, bias, out2,
                                          cen_sum, N, B);
    cen_fin_k<<<B, 64, 0, stream>>>(cen_sum, cen, cnorm);
    score_k<<<(N + 255) / 256, 256, 0, stream>>>(out2, cen, cnorm, score, N);
    softmax_kl_k<<<B, 256, 0, stream>>>(score, o_kl);
    sort_k<<<B, 1024, 0, stream>>>(score, sidx, o_ind);
    topk_k<<<(BK + 255) / 256, 256, 0, stream>>>(sidx, score, out2, mapping,
                                                 o_xnew, o_batch, o_perm, BK);
    edge_out_k<<<(E / 4 + 255) / 256, 256, 0, stream>>>(ei, eattr, mapping,
                                                        o_newei, o_eattr, o_mask, E);
}